// Round 2
// baseline (398.497 us; speedup 1.0000x reference)
//
#include <hip/hip_runtime.h>

// ---------------- problem constants ----------------
#define B_      8
#define A_      64
#define NPAIR   63
#define NC_     128
#define NF_     2560    // K
#define O2_     196     // 14*14
#define NORB_   14
#define AO_     896
#define NCOLS   588     // valid cols: [H_off 196 | S_off 196 | H_on 196]
#define CSTRIDE 640     // padded col stride of Bws/HSoff (=BN)
#define KSTEPS  80      // NF_/32
#define BM      128
#define BN      640

typedef short bf16x8 __attribute__((ext_vector_type(8)));
typedef float f32x4  __attribute__((ext_vector_type(4)));

__device__ __forceinline__ unsigned f2bf(float f) {
    unsigned u = __builtin_bit_cast(unsigned, f);
    return (u + 0x7fffu + ((u >> 16) & 1u)) >> 16;   // RNE
}

// ---------------- kernel 1: pack weights -> bf16 [ks][n=640][k=32], XOR-swizzled ----------------
// Swizzle baked into Bws so gemm's global_load_lds stays linear (rule #21):
// dest_byte = (n*64 + k*2) ^ ((n&7)<<4); reads apply the same XOR.
__global__ void prep_w(const float* __restrict__ W_off, const float* __restrict__ W_ovoff,
                       const float* __restrict__ W_on, unsigned short* __restrict__ Bws) {
    __shared__ float wt[32 * BN];
    const int ks = blockIdx.x, t = threadIdx.x;
    for (int e = t; e < 32 * BN; e += 256) {
        int kl = e / BN, c = e - kl * BN;
        int kg = ks * 32 + kl;
        float v = 0.f;
        if (c < O2_)          v = W_off  [(size_t)kg * O2_ + c];
        else if (c < 2 * O2_) v = W_ovoff[(size_t)kg * O2_ + (c - O2_)];
        else if (c < 3 * O2_) v = W_on   [(size_t)kg * O2_ + (c - 2 * O2_)];
        wt[kl * BN + c] = v;
    }
    __syncthreads();
    char* out = (char*)(Bws + (size_t)ks * (BN * 32));
    for (int e = t; e < BN * 4; e += 256) {
        int n = e >> 2, sg = e & 3;
        uint4 w;
        w.x = f2bf(wt[(sg * 8 + 0) * BN + n]) | (f2bf(wt[(sg * 8 + 1) * BN + n]) << 16);
        w.y = f2bf(wt[(sg * 8 + 2) * BN + n]) | (f2bf(wt[(sg * 8 + 3) * BN + n]) << 16);
        w.z = f2bf(wt[(sg * 8 + 4) * BN + n]) | (f2bf(wt[(sg * 8 + 5) * BN + n]) << 16);
        w.w = f2bf(wt[(sg * 8 + 6) * BN + n]) | (f2bf(wt[(sg * 8 + 7) * BN + n]) << 16);
        unsigned byte = ((unsigned)(n * 64 + sg * 16)) ^ ((unsigned)(n & 7) << 4);
        *(uint4*)(out + byte) = w;
    }
}

// ---------------- kernel 2: MFMA GEMM [32256 x 2560] x [2560 x 640(588 valid)] ----------------
// grid 252 M-tiles; 512 threads = 8 waves (2M x 4N), wave tile 64x160, acc[4][10].
__global__ __launch_bounds__(512, 1)
void gemm_off(const float* __restrict__ V, const unsigned short* __restrict__ Bws,
              const float* __restrict__ b_off, const float* __restrict__ b_ovoff,
              const float* __restrict__ b_on, float* __restrict__ HSoff) {
    __shared__ alignas(16) unsigned short Alds[2][BM * 40];   // rows padded 32->40 shorts (bank fix)
    __shared__ alignas(16) unsigned short Blds[2][BN * 32];   // linear dest, pre-swizzled content

    const int tid  = threadIdx.x;
    const int mt   = blockIdx.x;
    const int lane = tid & 63;
    const int wv   = tid >> 6;
    const int wm   = wv >> 2, wn = wv & 3;
    const int wvu  = __builtin_amdgcn_readfirstlane(wv);

    const int arow = tid >> 2, aseg = tid & 3;
    const float* aptr = V + (size_t)(mt * BM + arow) * NF_ + aseg * 8;

    f32x4 acc[4][10];
#pragma unroll
    for (int mf = 0; mf < 4; ++mf)
#pragma unroll
        for (int nf = 0; nf < 10; ++nf)
            acc[mf][nf] = (f32x4){0.f, 0.f, 0.f, 0.f};

    float4 pv0, pv1;

    auto issueB = [&](int bf, int ks) {
        const unsigned short* src = Bws + (size_t)ks * (BN * 32) + lane * 8;
        unsigned short* dst = &Blds[bf][0];
#pragma unroll
        for (int c = 0; c < 5; ++c) {
            int chunk = wvu + c * 8;                 // 8 waves x 5 = 40 KiB-chunks exactly
            __builtin_amdgcn_global_load_lds(
                (const __attribute__((address_space(1))) void*)(src + chunk * 512),
                (__attribute__((address_space(3))) void*)(dst + chunk * 512),
                16, 0, 0);
        }
    };
    auto loadA = [&](int ks) {
        const float* s = aptr + ks * 32;
        pv0 = ((const float4*)s)[0];
        pv1 = ((const float4*)s)[1];
    };
    auto writeA = [&](int bf) {
        uint4 w;
        w.x = f2bf(pv0.x) | (f2bf(pv0.y) << 16);
        w.y = f2bf(pv0.z) | (f2bf(pv0.w) << 16);
        w.z = f2bf(pv1.x) | (f2bf(pv1.y) << 16);
        w.w = f2bf(pv1.z) | (f2bf(pv1.w) << 16);
        *(uint4*)&Alds[bf][arow * 40 + aseg * 8] = w;
    };
    auto compute = [&](int bf) {
        bf16x8 af[4];
        const int ar = wm * 64 + (lane & 15);
        const int ko = (lane >> 4) * 8;
#pragma unroll
        for (int mf = 0; mf < 4; ++mf)
            af[mf] = *(const bf16x8*)&Alds[bf][(ar + mf * 16) * 40 + ko];
        const int nbase = wn * 160 + (lane & 15);
        const unsigned kb = (unsigned)(lane >> 4) * 16;
#pragma unroll
        for (int nf = 0; nf < 10; ++nf) {
            int n = nbase + nf * 16;
            unsigned byte = ((unsigned)(n * 64) + kb) ^ ((unsigned)(n & 7) << 4);
            bf16x8 bfr = *(const bf16x8*)((const char*)&Blds[bf][0] + byte);
#pragma unroll
            for (int mf = 0; mf < 4; ++mf)
                acc[mf][nf] = __builtin_amdgcn_mfma_f32_16x16x32_bf16(
                    af[mf], bfr, acc[mf][nf], 0, 0, 0);
        }
    };

    issueB(0, 0); loadA(0); writeA(0);
    __syncthreads();

    for (int ks = 0; ks < KSTEPS; ++ks) {
        const int cur = ks & 1, nxt = cur ^ 1;
        if (ks + 1 < KSTEPS) { issueB(nxt, ks + 1); loadA(ks + 1); }
        compute(cur);
        if (ks + 1 < KSTEPS) writeA(nxt);
        __syncthreads();
    }

    // C/D layout: col=lane&15, row=(lane>>4)*4+reg  [verified m89/m91, worked in R1]
    const int c16 = lane & 15, rg = lane >> 4;
#pragma unroll
    for (int nf = 0; nf < 10; ++nf) {
        int C = wn * 160 + nf * 16 + c16;
        if (C >= NCOLS) continue;
        float bias = (C < O2_) ? b_off[C] : (C < 2 * O2_) ? b_ovoff[C - O2_] : b_on[C - 2 * O2_];
#pragma unroll
        for (int mf = 0; mf < 4; ++mf) {
            int R = mt * BM + wm * 64 + mf * 16 + rg * 4;
            float* o = HSoff + (size_t)R * CSTRIDE + C;
            o[0]           = acc[mf][nf][0] + bias;
            o[CSTRIDE]     = acc[mf][nf][1] + bias;
            o[2 * CSTRIDE] = acc[mf][nf][2] + bias;
            o[3 * CSTRIDE] = acc[mf][nf][3] + bias;
        }
    }
}

// ---------------- kernel 3: Hon = rowmean over 63 pair rows of cols [392,588) ----------------
__global__ void hon_reduce(const float* __restrict__ HSoff, float* __restrict__ Hon) {
    const int g = blockIdx.x;       // 0..511
    const int t = threadIdx.x;      // 256, t<196 active
    if (t >= O2_) return;
    const float* p0 = HSoff + (size_t)g * NPAIR * CSTRIDE + 2 * O2_ + t;
    const float* p1 = p0 + (size_t)21 * CSTRIDE;
    const float* p2 = p0 + (size_t)42 * CSTRIDE;
    float a0 = 0.f, a1 = 0.f, a2 = 0.f;
#pragma unroll 3
    for (int j = 0; j < 21; ++j) {
        a0 += p0[0]; a1 += p1[0]; a2 += p2[0];
        p0 += CSTRIDE; p1 += CSTRIDE; p2 += CSTRIDE;
    }
    Hon[(size_t)g * O2_ + t] = (a0 + a1 + a2) * (1.f / (float)NPAIR);  // bias already in gemm
}

// ---------------- kernel 4: assemble H and S (coalesced writes) ----------------
// block = (b,i); threads sweep output row columns contiguously.
__global__ void assemble_k(const float* __restrict__ HSoff, const float* __restrict__ Hon,
                           const int* __restrict__ Z, const float* __restrict__ ov_emb,
                           const float* __restrict__ orbE, const float* __restrict__ s0E,
                           float* __restrict__ H, float* __restrict__ S) {
    const int bid = blockIdx.x;
    const int b = bid >> 6, i = bid & 63;
    const int t = threadIdx.x;
    const int z = Z[b * A_ + i];
    const float* hon = Hon + (size_t)(b * A_ + i) * O2_;
    const float* ov  = ov_emb + (size_t)z * O2_;
    for (int p = 0; p < NORB_; ++p) {
        const size_t rowbase = (size_t)b * AO_ * AO_ + (size_t)(i * NORB_ + p) * AO_;
        const float dE = orbE[(size_t)z * NORB_ + p];
        const float dS = s0E [(size_t)z * NORB_ + p];
        for (int c = t; c < AO_; c += 256) {
            int j = c / NORB_, q = c - j * NORB_;
            float h, s;
            if (j == i) {
                h = 0.5f * (hon[p * NORB_ + q] + hon[q * NORB_ + p]);
                s = 0.5f * (ov [p * NORB_ + q] + ov [q * NORB_ + p]);
                if (p == q) { h += dE; s += dS; }
            } else {
                const float* ha = HSoff + ((size_t)(b * A_ + i) * NPAIR + (j < i ? j : j - 1)) * CSTRIDE;
                const float* hb = HSoff + ((size_t)(b * A_ + j) * NPAIR + (i < j ? i : i - 1)) * CSTRIDE;
                h = 0.5f * (ha[p * NORB_ + q]       + hb[q * NORB_ + p]);
                s = 0.5f * (ha[O2_ + p * NORB_ + q] + hb[O2_ + q * NORB_ + p]);
            }
            H[rowbase + c] = h;
            S[rowbase + c] = s;
        }
    }
}

// ---------------- kernel 5: energy head ----------------
__global__ void energy_k(const float* __restrict__ x, const float* __restrict__ W1,
                         const float* __restrict__ b1, const float* __restrict__ W2,
                         const float* __restrict__ b2, float* __restrict__ E) {
    __shared__ float partial[8];
    const int b = blockIdx.x;
    const int lane = threadIdx.x & 63;
    const int w = threadIdx.x >> 6;
    float esum = 0.f;
    for (int aa = 0; aa < 8; ++aa) {
        const int a = w * 8 + aa;
        const float* xr = x + (size_t)(b * A_ + a) * NC_;
        float hj = b1[lane];
        for (int k = 0; k < NC_; ++k) hj = fmaf(xr[k], W1[k * 64 + lane], hj);
        float sp = fmaxf(hj, 0.f) + log1pf(expf(-fabsf(hj))) - 0.69314718055994531f;
        float v = sp * W2[lane];
        for (int off = 32; off; off >>= 1) v += __shfl_down(v, off);
        if (lane == 0) esum += v + b2[0];
    }
    if (lane == 0) partial[w] = esum;
    __syncthreads();
    if (threadIdx.x == 0) {
        float e = 0.f;
        for (int k = 0; k < 8; ++k) e += partial[k];
        E[b] = e;
    }
}

// ---------------- launcher ----------------
extern "C" void kernel_launch(void* const* d_in, const int* in_sizes, int n_in,
                              void* d_out, int out_size, void* d_ws, size_t ws_size,
                              hipStream_t stream) {
    const int*   Z       = (const int*)  d_in[0];
    const float* x       = (const float*)d_in[2];
    const float* V       = (const float*)d_in[3];
    const float* W_off   = (const float*)d_in[4];
    const float* b_off   = (const float*)d_in[5];
    const float* W_on    = (const float*)d_in[6];
    const float* b_on    = (const float*)d_in[7];
    const float* W_ovoff = (const float*)d_in[8];
    const float* b_ovoff = (const float*)d_in[9];
    const float* ov_emb  = (const float*)d_in[10];
    const float* orbE    = (const float*)d_in[11];
    const float* s0E     = (const float*)d_in[12];
    const float* W1      = (const float*)d_in[13];
    const float* b1      = (const float*)d_in[14];
    const float* W2      = (const float*)d_in[15];
    const float* b2      = (const float*)d_in[16];

    float* H = (float*)d_out;
    float* S = H + (size_t)B_ * AO_ * AO_;
    float* E = S + (size_t)B_ * AO_ * AO_;

    char* ws = (char*)d_ws;
    unsigned short* Bws = (unsigned short*)ws;                     //  3,276,800 B
    float* HSoff = (float*)(ws + (size_t)4  * 1024 * 1024);        // 82,575,360 B
    float* Hon   = (float*)(ws + (size_t)90 * 1024 * 1024);        //    401,408 B

    prep_w    <<<KSTEPS, 256, 0, stream>>>(W_off, W_ovoff, W_on, Bws);
    gemm_off  <<<252,    512, 0, stream>>>(V, Bws, b_off, b_ovoff, b_on, HSoff);
    hon_reduce<<<512,    256, 0, stream>>>(HSoff, Hon);
    assemble_k<<<512,    256, 0, stream>>>(HSoff, Hon, Z, ov_emb, orbE, s0E, H, S);
    energy_k  <<<8,      512, 0, stream>>>(x, W1, b1, W2, b2, E);
}

// Round 3
// 379.056 us; speedup vs baseline: 1.0513x; 1.0513x over previous
//
#include <hip/hip_runtime.h>

// ---------------- problem constants ----------------
#define B_      8
#define A_      64
#define NPAIR   63
#define NC_     128
#define NF_     2560    // K
#define O2_     196     // 14*14
#define NORB_   14
#define AO_     896
#define NCOLS   588     // valid cols: [H_off 196 | S_off 196 | H_on 196]
#define CSTRIDE 640     // padded col stride of HSoff
#define TCOLS   392     // transposed copy cols [H_off | S_off]
#define KSTEPS  80      // NF_/32
#define BM      128
#define BN      640

typedef short bf16x8 __attribute__((ext_vector_type(8)));
typedef float f32x4  __attribute__((ext_vector_type(4)));

__device__ __forceinline__ unsigned f2bf(float f) {
    unsigned u = __builtin_bit_cast(unsigned, f);
    return (u + 0x7fffu + ((u >> 16) & 1u)) >> 16;   // RNE
}

// ---------------- kernel 1: pack weights -> bf16 [ks][n=640][k=32], XOR-swizzled ----------------
__global__ void prep_w(const float* __restrict__ W_off, const float* __restrict__ W_ovoff,
                       const float* __restrict__ W_on, unsigned short* __restrict__ Bws) {
    __shared__ float wt[32 * BN];
    const int ks = blockIdx.x, t = threadIdx.x;
    for (int e = t; e < 32 * BN; e += 256) {
        int kl = e / BN, c = e - kl * BN;
        int kg = ks * 32 + kl;
        float v = 0.f;
        if (c < O2_)          v = W_off  [(size_t)kg * O2_ + c];
        else if (c < 2 * O2_) v = W_ovoff[(size_t)kg * O2_ + (c - O2_)];
        else if (c < 3 * O2_) v = W_on   [(size_t)kg * O2_ + (c - 2 * O2_)];
        wt[kl * BN + c] = v;
    }
    __syncthreads();
    char* out = (char*)(Bws + (size_t)ks * (BN * 32));
    for (int e = t; e < BN * 4; e += 256) {
        int n = e >> 2, sg = e & 3;
        uint4 w;
        w.x = f2bf(wt[(sg * 8 + 0) * BN + n]) | (f2bf(wt[(sg * 8 + 1) * BN + n]) << 16);
        w.y = f2bf(wt[(sg * 8 + 2) * BN + n]) | (f2bf(wt[(sg * 8 + 3) * BN + n]) << 16);
        w.z = f2bf(wt[(sg * 8 + 4) * BN + n]) | (f2bf(wt[(sg * 8 + 5) * BN + n]) << 16);
        w.w = f2bf(wt[(sg * 8 + 6) * BN + n]) | (f2bf(wt[(sg * 8 + 7) * BN + n]) << 16);
        unsigned byte = ((unsigned)(n * 64 + sg * 16)) ^ ((unsigned)(n & 7) << 4);
        *(uint4*)(out + byte) = w;
    }
}

// ---------------- kernel 2: MFMA GEMM, 4-phase K-steps, counted vmcnt, 3-buffer LDS ----------------
__global__ __launch_bounds__(512, 1)
void gemm_off(const float* __restrict__ V, const unsigned short* __restrict__ Bws,
              const float* __restrict__ b_off, const float* __restrict__ b_ovoff,
              const float* __restrict__ b_on, float* __restrict__ HSoff,
              float* __restrict__ HSoffT) {
    __shared__ alignas(16) unsigned short Alds[3][BM * 40];   // rows padded 32->40 shorts
    __shared__ alignas(16) unsigned short Blds[3][BN * 32];   // linear dest, pre-swizzled content

    const int tid  = threadIdx.x;
    const int mt   = blockIdx.x;
    const int lane = tid & 63;
    const int wv   = tid >> 6;
    const int wm   = wv >> 2, wn = wv & 3;
    const int wvu  = __builtin_amdgcn_readfirstlane(wv);

    const int arow = tid >> 2, aseg = tid & 3;
    const float* aptr = V + (size_t)(mt * BM + arow) * NF_ + aseg * 8;

    f32x4 acc[4][10];
#pragma unroll
    for (int mf = 0; mf < 4; ++mf)
#pragma unroll
        for (int nf = 0; nf < 10; ++nf)
            acc[mf][nf] = (f32x4){0.f, 0.f, 0.f, 0.f};

    float4 pv0, pv1;

    auto issueB1 = [&](int bufi, int ks, int c) {
        const int chunk = wvu + c * 8;                        // wave-uniform
        const unsigned short* src = Bws + (size_t)ks * (BN * 32) + (size_t)chunk * 512 + lane * 8;
        __builtin_amdgcn_global_load_lds(
            (const __attribute__((address_space(1))) void*)src,
            (__attribute__((address_space(3))) void*)(&Blds[bufi][chunk * 512]),
            16, 0, 0);
    };
    auto loadA = [&](int ks) {
        const float* s = aptr + ks * 32;
        pv0 = ((const float4*)s)[0];
        pv1 = ((const float4*)s)[1];
    };
    auto writeA = [&](int bufi) {
        uint4 w;
        w.x = f2bf(pv0.x) | (f2bf(pv0.y) << 16);
        w.y = f2bf(pv0.z) | (f2bf(pv0.w) << 16);
        w.z = f2bf(pv1.x) | (f2bf(pv1.y) << 16);
        w.w = f2bf(pv1.z) | (f2bf(pv1.w) << 16);
        *(uint4*)&Alds[bufi][arow * 40 + aseg * 8] = w;
    };

    const int ar    = wm * 64 + (lane & 15);
    const int ko    = (lane >> 4) * 8;                        // shorts
    const int nbase = wn * 160 + (lane & 15);
    const unsigned kb = (unsigned)(lane >> 4) * 16;           // bytes

#define RD_B(dst_, Bb_, nf_) {                                            \
    const int n_ = nbase + (nf_) * 16;                                    \
    const unsigned byte_ = ((unsigned)(n_ * 64) + kb) ^ ((unsigned)(n_ & 7) << 4); \
    dst_ = *(const bf16x8*)((const char*)(Bb_) + byte_); }

#define MFMA4(bv_, nf_) {                                                                  \
    acc[0][nf_] = __builtin_amdgcn_mfma_f32_16x16x32_bf16(af0, bv_, acc[0][nf_], 0, 0, 0); \
    acc[1][nf_] = __builtin_amdgcn_mfma_f32_16x16x32_bf16(af1, bv_, acc[1][nf_], 0, 0, 0); \
    acc[2][nf_] = __builtin_amdgcn_mfma_f32_16x16x32_bf16(af2, bv_, acc[2][nf_], 0, 0, 0); \
    acc[3][nf_] = __builtin_amdgcn_mfma_f32_16x16x32_bf16(af3, bv_, acc[3][nf_], 0, 0, 0); }

#define PHASE_SYNC()                                         \
    __builtin_amdgcn_sched_barrier(0);                       \
    __builtin_amdgcn_s_barrier();                            \
    asm volatile("s_waitcnt lgkmcnt(0)" ::: "memory");       \
    __builtin_amdgcn_sched_barrier(0);

    // ---- prologue: stage steps 0 and 1 ----
#pragma unroll
    for (int c = 0; c < 5; ++c) issueB1(0, 0, c);
    loadA(0);
    asm volatile("s_waitcnt vmcnt(0)" ::: "memory");
    writeA(0);
#pragma unroll
    for (int c = 0; c < 5; ++c) issueB1(1, 1, c);
    loadA(1);                                    // pv holds A(1); written at p3 of t=0
    asm volatile("s_waitcnt lgkmcnt(0)" ::: "memory");
    __builtin_amdgcn_sched_barrier(0);
    __builtin_amdgcn_s_barrier();

    int cb = 0, n1 = 1, n2 = 2;
    for (int t = 0; t < KSTEPS; ++t) {
        const bool h2 = (t + 2 < KSTEPS), h1 = (t + 1 < KSTEPS);
        const unsigned short* Ab = &Alds[cb][0];
        const char* Bb = (const char*)&Blds[cb][0];
        bf16x8 af0, af1, af2, af3, b0, b1, b2;

        // ---- p0: A-frags + B nf0-2; stage 2 B(t+2); 12 MFMA ----
        af0 = *(const bf16x8*)&Ab[(ar +  0) * 40 + ko];
        af1 = *(const bf16x8*)&Ab[(ar + 16) * 40 + ko];
        af2 = *(const bf16x8*)&Ab[(ar + 32) * 40 + ko];
        af3 = *(const bf16x8*)&Ab[(ar + 48) * 40 + ko];
        RD_B(b0, Bb, 0); RD_B(b1, Bb, 1); RD_B(b2, Bb, 2);
        if (h2) { issueB1(n2, t + 2, 0); issueB1(n2, t + 2, 1); }
        PHASE_SYNC();
        __builtin_amdgcn_s_setprio(1);
        MFMA4(b0, 0); MFMA4(b1, 1); MFMA4(b2, 2);
        __builtin_amdgcn_s_setprio(0);
        __builtin_amdgcn_s_barrier();

        // ---- p1: B nf3-5; stage 2 B(t+2); 12 MFMA ----
        RD_B(b0, Bb, 3); RD_B(b1, Bb, 4); RD_B(b2, Bb, 5);
        if (h2) { issueB1(n2, t + 2, 2); issueB1(n2, t + 2, 3); }
        PHASE_SYNC();
        __builtin_amdgcn_s_setprio(1);
        MFMA4(b0, 3); MFMA4(b1, 4); MFMA4(b2, 5);
        __builtin_amdgcn_s_setprio(0);
        __builtin_amdgcn_s_barrier();

        // ---- p2: B nf6-7; stage 1 B(t+2); 8 MFMA ----
        RD_B(b0, Bb, 6); RD_B(b1, Bb, 7);
        if (h2) issueB1(n2, t + 2, 4);
        PHASE_SYNC();
        __builtin_amdgcn_s_setprio(1);
        MFMA4(b0, 6); MFMA4(b1, 7);
        __builtin_amdgcn_s_setprio(0);
        __builtin_amdgcn_s_barrier();

        // ---- p3: B nf8-9; A write(t+1) under counted vmcnt; issue A(t+2); 8 MFMA ----
        RD_B(b0, Bb, 8); RD_B(b1, Bb, 9);
        if (h1) {
            if (h2) asm volatile("s_waitcnt vmcnt(5)" ::: "memory");  // retire B(t+1)+A(t+1); keep B(t+2) flying
            else    asm volatile("s_waitcnt vmcnt(0)" ::: "memory");
            writeA(n1);
            if (h2) loadA(t + 2);
        }
        PHASE_SYNC();
        __builtin_amdgcn_s_setprio(1);
        MFMA4(b0, 8); MFMA4(b1, 9);
        __builtin_amdgcn_s_setprio(0);
        __builtin_amdgcn_s_barrier();                                  // end of step

        const int tmp = cb; cb = n1; n1 = n2; n2 = tmp;
    }

    // ---- epilogue: C/D layout col=lane&15, row=(lane>>4)*4+reg; + block-transposed copy ----
    const int c16 = lane & 15, rg = lane >> 4;
#pragma unroll
    for (int nf = 0; nf < 10; ++nf) {
        int C = wn * 160 + nf * 16 + c16;
        if (C >= NCOLS) continue;
        float bias = (C < O2_) ? b_off[C] : (C < 2 * O2_) ? b_ovoff[C - O2_] : b_on[C - 2 * O2_];
#pragma unroll
        for (int mf = 0; mf < 4; ++mf) {
            int R = mt * BM + wm * 64 + mf * 16 + rg * 4;
            float v0 = acc[mf][nf][0] + bias;
            float v1 = acc[mf][nf][1] + bias;
            float v2 = acc[mf][nf][2] + bias;
            float v3 = acc[mf][nf][3] + bias;
            float* o = HSoff + (size_t)R * CSTRIDE + C;
            o[0] = v0; o[CSTRIDE] = v1; o[2 * CSTRIDE] = v2; o[3 * CSTRIDE] = v3;
            if (C < TCOLS) {
                int half = (C < O2_) ? 0 : 1;
                int cc = C - half * O2_;
                int p = cc / NORB_, q = cc - p * NORB_;
                int ct = half * O2_ + q * NORB_ + p;
                float* oT = HSoffT + (size_t)R * TCOLS + ct;
                oT[0] = v0; oT[TCOLS] = v1; oT[2 * TCOLS] = v2; oT[3 * TCOLS] = v3;
            }
        }
    }
#undef RD_B
#undef MFMA4
#undef PHASE_SYNC
}

// ---------------- kernel 3: Hon = rowmean over 63 pair rows of cols [392,588) ----------------
__global__ void hon_reduce(const float* __restrict__ HSoff, float* __restrict__ Hon) {
    const int g = blockIdx.x;       // 0..511
    const int t = threadIdx.x;      // 256, t<196 active
    if (t >= O2_) return;
    const float* p0 = HSoff + (size_t)g * NPAIR * CSTRIDE + 2 * O2_ + t;
    const float* p1 = p0 + (size_t)21 * CSTRIDE;
    const float* p2 = p0 + (size_t)42 * CSTRIDE;
    float a0 = 0.f, a1 = 0.f, a2 = 0.f;
#pragma unroll 3
    for (int j = 0; j < 21; ++j) {
        a0 += p0[0]; a1 += p1[0]; a2 += p2[0];
        p0 += CSTRIDE; p1 += CSTRIDE; p2 += CSTRIDE;
    }
    Hon[(size_t)g * O2_ + t] = (a0 + a1 + a2) * (1.f / (float)NPAIR);
}

// ---------------- kernel 4: assemble H and S (streaming reads via HSoffT) ----------------
__global__ void assemble_k(const float* __restrict__ HSoff, const float* __restrict__ HSoffT,
                           const float* __restrict__ Hon,
                           const int* __restrict__ Z, const float* __restrict__ ov_emb,
                           const float* __restrict__ orbE, const float* __restrict__ s0E,
                           float* __restrict__ H, float* __restrict__ S) {
    const int bid = blockIdx.x;
    const int b = bid >> 6, i = bid & 63;
    const int t = threadIdx.x;
    const int z = Z[b * A_ + i];
    const float* hon = Hon + (size_t)(b * A_ + i) * O2_;
    const float* ov  = ov_emb + (size_t)z * O2_;
    for (int p = 0; p < NORB_; ++p) {
        const size_t rowbase = (size_t)b * AO_ * AO_ + (size_t)(i * NORB_ + p) * AO_;
        const float dE = orbE[(size_t)z * NORB_ + p];
        const float dS = s0E [(size_t)z * NORB_ + p];
        for (int c = t; c < AO_; c += 256) {
            int j = c / NORB_, q = c - j * NORB_;
            float h, s;
            if (j == i) {
                h = 0.5f * (hon[p * NORB_ + q] + hon[q * NORB_ + p]);
                s = 0.5f * (ov [p * NORB_ + q] + ov [q * NORB_ + p]);
                if (p == q) { h += dE; s += dS; }
            } else {
                const float* ha = HSoff  + ((size_t)(b * A_ + i) * NPAIR + (j < i ? j : j - 1)) * CSTRIDE;
                const float* hb = HSoffT + ((size_t)(b * A_ + j) * NPAIR + (i < j ? i : i - 1)) * TCOLS;
                const int o = p * NORB_ + q;
                h = 0.5f * (ha[o]       + hb[o]);
                s = 0.5f * (ha[O2_ + o] + hb[O2_ + o]);
            }
            H[rowbase + c] = h;
            S[rowbase + c] = s;
        }
    }
}

// ---------------- kernel 5: energy head ----------------
__global__ void energy_k(const float* __restrict__ x, const float* __restrict__ W1,
                         const float* __restrict__ b1, const float* __restrict__ W2,
                         const float* __restrict__ b2, float* __restrict__ E) {
    __shared__ float partial[8];
    const int b = blockIdx.x;
    const int lane = threadIdx.x & 63;
    const int w = threadIdx.x >> 6;
    float esum = 0.f;
    for (int aa = 0; aa < 8; ++aa) {
        const int a = w * 8 + aa;
        const float* xr = x + (size_t)(b * A_ + a) * NC_;
        float hj = b1[lane];
        for (int k = 0; k < NC_; ++k) hj = fmaf(xr[k], W1[k * 64 + lane], hj);
        float sp = fmaxf(hj, 0.f) + log1pf(expf(-fabsf(hj))) - 0.69314718055994531f;
        float v = sp * W2[lane];
        for (int off = 32; off; off >>= 1) v += __shfl_down(v, off);
        if (lane == 0) esum += v + b2[0];
    }
    if (lane == 0) partial[w] = esum;
    __syncthreads();
    if (threadIdx.x == 0) {
        float e = 0.f;
        for (int k = 0; k < 8; ++k) e += partial[k];
        E[b] = e;
    }
}

// ---------------- launcher ----------------
extern "C" void kernel_launch(void* const* d_in, const int* in_sizes, int n_in,
                              void* d_out, int out_size, void* d_ws, size_t ws_size,
                              hipStream_t stream) {
    const int*   Z       = (const int*)  d_in[0];
    const float* x       = (const float*)d_in[2];
    const float* V       = (const float*)d_in[3];
    const float* W_off   = (const float*)d_in[4];
    const float* b_off   = (const float*)d_in[5];
    const float* W_on    = (const float*)d_in[6];
    const float* b_on    = (const float*)d_in[7];
    const float* W_ovoff = (const float*)d_in[8];
    const float* b_ovoff = (const float*)d_in[9];
    const float* ov_emb  = (const float*)d_in[10];
    const float* orbE    = (const float*)d_in[11];
    const float* s0E     = (const float*)d_in[12];
    const float* W1      = (const float*)d_in[13];
    const float* b1      = (const float*)d_in[14];
    const float* W2      = (const float*)d_in[15];
    const float* b2      = (const float*)d_in[16];

    float* H = (float*)d_out;
    float* S = H + (size_t)B_ * AO_ * AO_;
    float* E = S + (size_t)B_ * AO_ * AO_;

    char* ws = (char*)d_ws;
    unsigned short* Bws = (unsigned short*)ws;                     //  3,276,800 B
    float* HSoff  = (float*)(ws + (size_t)4  * 1024 * 1024);       // 82,575,360 B
    float* Hon    = (float*)(ws + (size_t)88 * 1024 * 1024);       //    401,408 B
    float* HSoffT = (float*)(ws + (size_t)90 * 1024 * 1024);       // 50,577,408 B

    prep_w    <<<KSTEPS, 256, 0, stream>>>(W_off, W_ovoff, W_on, Bws);
    gemm_off  <<<252,    512, 0, stream>>>(V, Bws, b_off, b_ovoff, b_on, HSoff, HSoffT);
    hon_reduce<<<512,    256, 0, stream>>>(HSoff, Hon);
    assemble_k<<<512,    256, 0, stream>>>(HSoff, HSoffT, Hon, Z, ov_emb, orbE, s0E, H, S);
    energy_k  <<<8,      512, 0, stream>>>(x, W1, b1, W2, b2, E);
}

// Round 4
// 308.825 us; speedup vs baseline: 1.2904x; 1.2274x over previous
//
#include <hip/hip_runtime.h>

// ---------------- problem constants ----------------
#define B_      8
#define A_      64
#define NPAIR   63
#define NC_     128
#define NF_     2560    // K
#define O2_     196     // 14*14
#define NORB_   14
#define AO_     896
#define NCOLS   588     // valid cols: [H_off 196 | S_off 196 | H_on 196]
#define CSTRIDE 640     // padded col stride of HSoff
#define KSTEPS  80      // NF_/32
#define BM      128
#define BN      640

typedef short bf16x8 __attribute__((ext_vector_type(8)));
typedef float f32x4  __attribute__((ext_vector_type(4)));

__device__ __forceinline__ unsigned f2bf(float f) {
    unsigned u = __builtin_bit_cast(unsigned, f);
    return (u + 0x7fffu + ((u >> 16) & 1u)) >> 16;   // RNE
}

// ---------------- kernel 1: pack weights -> bf16 [ks][n=640][k=32], XOR-swizzled ----------------
// dest_byte = (n*64 + k*2) ^ ((n&7)<<4); gemm reads apply the same XOR.
__global__ void prep_w(const float* __restrict__ W_off, const float* __restrict__ W_ovoff,
                       const float* __restrict__ W_on, unsigned short* __restrict__ Bws) {
    __shared__ float wt[32 * BN];
    const int ks = blockIdx.x, t = threadIdx.x;
    for (int e = t; e < 32 * BN; e += 256) {
        int kl = e / BN, c = e - kl * BN;
        int kg = ks * 32 + kl;
        float v = 0.f;
        if (c < O2_)          v = W_off  [(size_t)kg * O2_ + c];
        else if (c < 2 * O2_) v = W_ovoff[(size_t)kg * O2_ + (c - O2_)];
        else if (c < 3 * O2_) v = W_on   [(size_t)kg * O2_ + (c - 2 * O2_)];
        wt[kl * BN + c] = v;
    }
    __syncthreads();
    char* out = (char*)(Bws + (size_t)ks * (BN * 32));
    for (int e = t; e < BN * 4; e += 256) {
        int n = e >> 2, sg = e & 3;
        uint4 w;
        w.x = f2bf(wt[(sg * 8 + 0) * BN + n]) | (f2bf(wt[(sg * 8 + 1) * BN + n]) << 16);
        w.y = f2bf(wt[(sg * 8 + 2) * BN + n]) | (f2bf(wt[(sg * 8 + 3) * BN + n]) << 16);
        w.z = f2bf(wt[(sg * 8 + 4) * BN + n]) | (f2bf(wt[(sg * 8 + 5) * BN + n]) << 16);
        w.w = f2bf(wt[(sg * 8 + 6) * BN + n]) | (f2bf(wt[(sg * 8 + 7) * BN + n]) << 16);
        unsigned byte = ((unsigned)(n * 64 + sg * 16)) ^ ((unsigned)(n & 7) << 4);
        *(uint4*)(out + byte) = w;
    }
}

// ---------------- kernel 2: MFMA GEMM, 16 waves (4x4), wave-tile 32x160, acc[2][10]=80 VGPR ----------------
__global__ __launch_bounds__(1024, 4)
void gemm_off(const float* __restrict__ V, const unsigned short* __restrict__ Bws,
              const float* __restrict__ b_off, const float* __restrict__ b_ovoff,
              const float* __restrict__ b_on, float* __restrict__ HSoff) {
    __shared__ alignas(16) unsigned short Alds[2][BM * 32];   // rows 64B, XOR-swizzled
    __shared__ alignas(16) unsigned short Blds[2][BN * 32];   // linear dest, pre-swizzled content

    const int tid  = threadIdx.x;
    const int mt   = blockIdx.x;
    const int lane = tid & 63;
    const int wv   = tid >> 6;
    const int wm   = wv >> 2, wn = wv & 3;
    const int wvu  = __builtin_amdgcn_readfirstlane(wv);

    const int arow = tid >> 3, aseg = tid & 7;                // 128 rows x 8 segs of 4 floats
    const float* aptr = V + (size_t)(mt * BM + arow) * NF_ + aseg * 4;

    f32x4 acc[2][10];
#pragma unroll
    for (int mf = 0; mf < 2; ++mf)
#pragma unroll
        for (int nf = 0; nf < 10; ++nf)
            acc[mf][nf] = (f32x4){0.f, 0.f, 0.f, 0.f};

    float4 pv;

    auto issueB = [&](int bf, int ks) {
        const unsigned short* src0 = Bws + (size_t)ks * (BN * 32) + lane * 8;
        unsigned short* dst0 = &Blds[bf][0];
        {   // chunk wvu
            __builtin_amdgcn_global_load_lds(
                (const __attribute__((address_space(1))) void*)(src0 + wvu * 512),
                (__attribute__((address_space(3))) void*)(dst0 + wvu * 512), 16, 0, 0);
        }
        {   // chunk wvu+16
            __builtin_amdgcn_global_load_lds(
                (const __attribute__((address_space(1))) void*)(src0 + (wvu + 16) * 512),
                (__attribute__((address_space(3))) void*)(dst0 + (wvu + 16) * 512), 16, 0, 0);
        }
        if (wvu < 8) {  // chunk wvu+32
            __builtin_amdgcn_global_load_lds(
                (const __attribute__((address_space(1))) void*)(src0 + (wvu + 32) * 512),
                (__attribute__((address_space(3))) void*)(dst0 + (wvu + 32) * 512), 16, 0, 0);
        }
    };
    auto loadA = [&](int ks) {
        pv = *(const float4*)(aptr + ks * 32);
    };
    auto writeA = [&](int bf) {
        uint2 w;
        w.x = f2bf(pv.x) | (f2bf(pv.y) << 16);
        w.y = f2bf(pv.z) | (f2bf(pv.w) << 16);
        unsigned byte = ((unsigned)(arow * 64 + aseg * 8)) ^ ((unsigned)(arow & 7) << 4);
        *(uint2*)((char*)&Alds[bf][0] + byte) = w;
    };
    auto compute = [&](int bf) {
        const int r0 = wm * 32 + (lane & 15);
        const int r1 = r0 + 16;
        const unsigned kb = (unsigned)(lane >> 4) * 16;
        const unsigned ab0 = ((unsigned)(r0 * 64) + kb) ^ ((unsigned)(r0 & 7) << 4);
        const unsigned ab1 = ((unsigned)(r1 * 64) + kb) ^ ((unsigned)(r1 & 7) << 4);
        bf16x8 af0 = *(const bf16x8*)((const char*)&Alds[bf][0] + ab0);
        bf16x8 af1 = *(const bf16x8*)((const char*)&Alds[bf][0] + ab1);
        const int nbase = wn * 160 + (lane & 15);
        const char* Bb = (const char*)&Blds[bf][0];
        bf16x8 bfr[2];
        {
            const int n0 = nbase;
            const unsigned b0 = ((unsigned)(n0 * 64) + kb) ^ ((unsigned)(n0 & 7) << 4);
            bfr[0] = *(const bf16x8*)(Bb + b0);
        }
#pragma unroll
        for (int nf = 0; nf < 10; ++nf) {
            if (nf < 9) {
                const int nn = nbase + (nf + 1) * 16;
                const unsigned bb = ((unsigned)(nn * 64) + kb) ^ ((unsigned)(nn & 7) << 4);
                bfr[(nf + 1) & 1] = *(const bf16x8*)(Bb + bb);
            }
            acc[0][nf] = __builtin_amdgcn_mfma_f32_16x16x32_bf16(af0, bfr[nf & 1], acc[0][nf], 0, 0, 0);
            acc[1][nf] = __builtin_amdgcn_mfma_f32_16x16x32_bf16(af1, bfr[nf & 1], acc[1][nf], 0, 0, 0);
        }
    };

    issueB(0, 0); loadA(0); writeA(0);
    __syncthreads();

    for (int ks = 0; ks < KSTEPS; ++ks) {
        const int cur = ks & 1, nxt = cur ^ 1;
        if (ks + 1 < KSTEPS) { issueB(nxt, ks + 1); loadA(ks + 1); }
        compute(cur);
        if (ks + 1 < KSTEPS) writeA(nxt);
        __syncthreads();
    }

    // epilogue: C/D layout col=lane&15, row=(lane>>4)*4+reg
    const int c16 = lane & 15, rg = lane >> 4;
#pragma unroll
    for (int nf = 0; nf < 10; ++nf) {
        int C = wn * 160 + nf * 16 + c16;
        if (C >= NCOLS) continue;
        float bias = (C < O2_) ? b_off[C] : (C < 2 * O2_) ? b_ovoff[C - O2_] : b_on[C - 2 * O2_];
#pragma unroll
        for (int mf = 0; mf < 2; ++mf) {
            int R = mt * BM + wm * 32 + mf * 16 + rg * 4;
            float* o = HSoff + (size_t)R * CSTRIDE + C;
            o[0]           = acc[mf][nf][0] + bias;
            o[CSTRIDE]     = acc[mf][nf][1] + bias;
            o[2 * CSTRIDE] = acc[mf][nf][2] + bias;
            o[3 * CSTRIDE] = acc[mf][nf][3] + bias;
        }
    }
}

// ---------------- kernel 3: Hon = rowmean over 63 pair rows of cols [392,588) ----------------
__global__ void hon_reduce(const float* __restrict__ HSoff, float* __restrict__ Hon) {
    const int g = blockIdx.x;       // 0..511
    const int t = threadIdx.x;      // 256, t<196 active
    if (t >= O2_) return;
    const float* p0 = HSoff + (size_t)g * NPAIR * CSTRIDE + 2 * O2_ + t;
    const float* p1 = p0 + (size_t)21 * CSTRIDE;
    const float* p2 = p0 + (size_t)42 * CSTRIDE;
    float a0 = 0.f, a1 = 0.f, a2 = 0.f;
#pragma unroll 3
    for (int j = 0; j < 21; ++j) {
        a0 += p0[0]; a1 += p1[0]; a2 += p2[0];
        p0 += CSTRIDE; p1 += CSTRIDE; p2 += CSTRIDE;
    }
    Hon[(size_t)g * O2_ + t] = (a0 + a1 + a2) * (1.f / (float)NPAIR);
}

// ---------------- kernel 4: assemble H and S, LDS-staged, fully coalesced ----------------
// block = (b, i, half): stages Ai panel (63x196) once + Bj 16-row chunks (dbuf);
// symmetrization transpose happens in LDS; writes are contiguous 896B rows.
__global__ __launch_bounds__(256)
void assemble_k(const float* __restrict__ HSoff, const float* __restrict__ Hon,
                const int* __restrict__ Z, const float* __restrict__ ov_emb,
                const float* __restrict__ orbE, const float* __restrict__ s0E,
                float* __restrict__ H, float* __restrict__ S) {
    __shared__ float Ai[NPAIR * 197];
    __shared__ float Bj[2][16 * 200];
    __shared__ float Dg[O2_];
    __shared__ float Dd[NORB_];

    const int bid = blockIdx.x;
    const int h = bid & 1, i = (bid >> 1) & 63, b = bid >> 7;
    const int t = threadIdx.x;
    const int g = b * A_ + i;
    const int z = Z[g];
    float* out = (h ? S : H) + (size_t)b * AO_ * AO_;

    const float* abase = HSoff + (size_t)g * NPAIR * CSTRIDE + h * O2_;
    for (int u = t; u < NPAIR * O2_; u += 256) {
        int jj = u / O2_, e = u - jj * O2_;
        Ai[jj * 197 + e] = abase[(size_t)jj * CSTRIDE + e];
    }
    if (t < O2_)   Dg[t] = h ? ov_emb[(size_t)z * O2_ + t]   : Hon[(size_t)g * O2_ + t];
    if (t < NORB_) Dd[t] = h ? s0E[(size_t)z * NORB_ + t]    : orbE[(size_t)z * NORB_ + t];

    auto stageB = [&](int buf, int jc) {
        for (int u = t; u < 16 * O2_; u += 256) {
            int jl = u / O2_, e = u - jl * O2_;
            int j = jc * 16 + jl;
            if (j != i) {
                int idx = (i < j) ? i : i - 1;
                Bj[buf][jl * 200 + e] =
                    HSoff[((size_t)(b * A_ + j) * NPAIR + idx) * CSTRIDE + h * O2_ + e];
            }
        }
    };
    stageB(0, 0);
    __syncthreads();

    const int tj = t / NORB_, tq = t - tj * NORB_;   // valid for t<224
    for (int jc = 0; jc < 4; ++jc) {
        if (jc < 3) stageB((jc + 1) & 1, jc + 1);
        if (t < 224) {
            const int j = jc * 16 + tj;
            const int cur = jc & 1;
#pragma unroll
            for (int p = 0; p < NORB_; ++p) {
                float v;
                if (j == i) {
                    v = 0.5f * (Dg[p * NORB_ + tq] + Dg[tq * NORB_ + p]);
                    if (p == tq) v += Dd[p];
                } else {
                    int jj = (j < i) ? j : j - 1;
                    v = 0.5f * (Ai[jj * 197 + p * NORB_ + tq] + Bj[cur][tj * 200 + tq * NORB_ + p]);
                }
                out[(size_t)(i * NORB_ + p) * AO_ + jc * 224 + t] = v;
            }
        }
        __syncthreads();
    }
}

// ---------------- kernel 5: energy head ----------------
__global__ void energy_k(const float* __restrict__ x, const float* __restrict__ W1,
                         const float* __restrict__ b1, const float* __restrict__ W2,
                         const float* __restrict__ b2, float* __restrict__ E) {
    __shared__ float partial[8];
    const int b = blockIdx.x;
    const int lane = threadIdx.x & 63;
    const int w = threadIdx.x >> 6;
    float esum = 0.f;
    for (int aa = 0; aa < 8; ++aa) {
        const int a = w * 8 + aa;
        const float* xr = x + (size_t)(b * A_ + a) * NC_;
        float hj = b1[lane];
        for (int k = 0; k < NC_; ++k) hj = fmaf(xr[k], W1[k * 64 + lane], hj);
        float sp = fmaxf(hj, 0.f) + log1pf(expf(-fabsf(hj))) - 0.69314718055994531f;
        float v = sp * W2[lane];
        for (int off = 32; off; off >>= 1) v += __shfl_down(v, off);
        if (lane == 0) esum += v + b2[0];
    }
    if (lane == 0) partial[w] = esum;
    __syncthreads();
    if (threadIdx.x == 0) {
        float e = 0.f;
        for (int k = 0; k < 8; ++k) e += partial[k];
        E[b] = e;
    }
}

// ---------------- launcher ----------------
extern "C" void kernel_launch(void* const* d_in, const int* in_sizes, int n_in,
                              void* d_out, int out_size, void* d_ws, size_t ws_size,
                              hipStream_t stream) {
    const int*   Z       = (const int*)  d_in[0];
    const float* x       = (const float*)d_in[2];
    const float* V       = (const float*)d_in[3];
    const float* W_off   = (const float*)d_in[4];
    const float* b_off   = (const float*)d_in[5];
    const float* W_on    = (const float*)d_in[6];
    const float* b_on    = (const float*)d_in[7];
    const float* W_ovoff = (const float*)d_in[8];
    const float* b_ovoff = (const float*)d_in[9];
    const float* ov_emb  = (const float*)d_in[10];
    const float* orbE    = (const float*)d_in[11];
    const float* s0E     = (const float*)d_in[12];
    const float* W1      = (const float*)d_in[13];
    const float* b1      = (const float*)d_in[14];
    const float* W2      = (const float*)d_in[15];
    const float* b2      = (const float*)d_in[16];

    float* H = (float*)d_out;
    float* S = H + (size_t)B_ * AO_ * AO_;
    float* E = S + (size_t)B_ * AO_ * AO_;

    char* ws = (char*)d_ws;
    unsigned short* Bws = (unsigned short*)ws;                     //  3,276,800 B
    float* HSoff = (float*)(ws + (size_t)4  * 1024 * 1024);        // 82,575,360 B
    float* Hon   = (float*)(ws + (size_t)88 * 1024 * 1024);        //    401,408 B

    prep_w    <<<KSTEPS, 256,  0, stream>>>(W_off, W_ovoff, W_on, Bws);
    gemm_off  <<<252,    1024, 0, stream>>>(V, Bws, b_off, b_ovoff, b_on, HSoff);
    hon_reduce<<<512,    256,  0, stream>>>(HSoff, Hon);
    assemble_k<<<1024,   256,  0, stream>>>(HSoff, Hon, Z, ov_emb, orbE, s0E, H, S);
    energy_k  <<<8,      512,  0, stream>>>(x, W1, b1, W2, b2, E);
}

// Round 5
// 307.460 us; speedup vs baseline: 1.2961x; 1.0044x over previous
//
#include <hip/hip_runtime.h>

// ---------------- problem constants ----------------
#define B_      8
#define A_      64
#define NPAIR   63
#define NC_     128
#define NF_     2560    // K
#define O2_     196     // 14*14
#define NORB_   14
#define AO_     896
#define NCOLS   588     // valid cols: [H_off 196 | S_off 196 | H_on 196]
#define CSTRIDE 640     // padded col stride of HSoff
#define KSTEPS  80      // NF_/32
#define BM      128
#define BN      640
#define BSTEP_BYTES 40960   // BN*32*2 per K-step

typedef short bf16x8 __attribute__((ext_vector_type(8)));
typedef float f32x4  __attribute__((ext_vector_type(4)));

__device__ __forceinline__ unsigned f2bf(float f) {
    unsigned u = __builtin_bit_cast(unsigned, f);
    return (u + 0x7fffu + ((u >> 16) & 1u)) >> 16;   // RNE
}

// ---------------- kernel 1: pack weights -> bf16 [ks][n=640][k=32], LINEAR (B read from L2) ----------------
__global__ void prep_w(const float* __restrict__ W_off, const float* __restrict__ W_ovoff,
                       const float* __restrict__ W_on, unsigned short* __restrict__ Bws) {
    __shared__ float wt[32 * BN];
    const int ks = blockIdx.x, t = threadIdx.x;
    for (int e = t; e < 32 * BN; e += 256) {
        int kl = e / BN, c = e - kl * BN;
        int kg = ks * 32 + kl;
        float v = 0.f;
        if (c < O2_)          v = W_off  [(size_t)kg * O2_ + c];
        else if (c < 2 * O2_) v = W_ovoff[(size_t)kg * O2_ + (c - O2_)];
        else if (c < 3 * O2_) v = W_on   [(size_t)kg * O2_ + (c - 2 * O2_)];
        wt[kl * BN + c] = v;
    }
    __syncthreads();
    unsigned short* out = Bws + (size_t)ks * (BN * 32);
    for (int e = t; e < BN * 4; e += 256) {
        int n = e >> 2, sg = e & 3;
        uint4 w;
        w.x = f2bf(wt[(sg * 8 + 0) * BN + n]) | (f2bf(wt[(sg * 8 + 1) * BN + n]) << 16);
        w.y = f2bf(wt[(sg * 8 + 2) * BN + n]) | (f2bf(wt[(sg * 8 + 3) * BN + n]) << 16);
        w.z = f2bf(wt[(sg * 8 + 4) * BN + n]) | (f2bf(wt[(sg * 8 + 5) * BN + n]) << 16);
        w.w = f2bf(wt[(sg * 8 + 6) * BN + n]) | (f2bf(wt[(sg * 8 + 7) * BN + n]) << 16);
        *(uint4*)(out + (size_t)n * 32 + sg * 8) = w;
    }
}

// ---------------- kernel 2: MFMA GEMM; A in LDS (dbuf), B global->reg 5-slot rolling prefetch ----------------
// 8 waves (2M x 4N), wave-tile 64x160, acc[4][10]=160 VGPR.
__global__ __launch_bounds__(512, 2)
void gemm_off(const float* __restrict__ V, const unsigned short* __restrict__ Bws,
              const float* __restrict__ b_off, const float* __restrict__ b_ovoff,
              const float* __restrict__ b_on, float* __restrict__ HSoff) {
    __shared__ alignas(16) unsigned short Alds[2][BM * 32];   // 64B rows, XOR-swizzled (conflict-free)

    const int tid  = threadIdx.x;
    const int mt   = blockIdx.x;
    const int lane = tid & 63;
    const int wv   = tid >> 6;
    const int wm   = wv >> 2, wn = wv & 3;

    const int arow = tid >> 2, aseg = tid & 3;                // 128 rows x 4 segs x 8 floats
    const float* aptr = V + (size_t)(mt * BM + arow) * NF_ + aseg * 8;

    // per-lane B fragment base (bytes into Bws)
    const char* bp = (const char*)Bws + (size_t)(wn * 160 + (lane & 15)) * 64 + (lane >> 4) * 16;
#define BFRAG(t_, nf_) (*(const bf16x8*)(bp + (size_t)(t_) * BSTEP_BYTES + (nf_) * 1024))

    f32x4 acc[4][10];
#pragma unroll
    for (int mf = 0; mf < 4; ++mf)
#pragma unroll
        for (int nf = 0; nf < 10; ++nf)
            acc[mf][nf] = (f32x4){0.f, 0.f, 0.f, 0.f};

    float4 pv0, pv1;
    auto loadA = [&](int ks) {
        const float* s = aptr + ks * 32;
        pv0 = ((const float4*)s)[0];
        pv1 = ((const float4*)s)[1];
    };
    auto writeA = [&](int bf) {
        uint4 w;
        w.x = f2bf(pv0.x) | (f2bf(pv0.y) << 16);
        w.y = f2bf(pv0.z) | (f2bf(pv0.w) << 16);
        w.z = f2bf(pv1.x) | (f2bf(pv1.y) << 16);
        w.w = f2bf(pv1.z) | (f2bf(pv1.w) << 16);
        unsigned byte = ((unsigned)(arow * 64 + aseg * 16)) ^ ((unsigned)(arow & 7) << 4);
        *(uint4*)((char*)&Alds[bf][0] + byte) = w;
    };

    const int ar = wm * 64 + (lane & 15);
    const unsigned kb = (unsigned)(lane >> 4) * 16;           // byte slice within row

#define ARD(mf_) (*(const bf16x8*)((const char*)Ab + ((((unsigned)((ar + (mf_) * 16) * 64) + kb)) ^ ((unsigned)(ar & 7) << 4))))

#define MFMA4(bv_, nf_) {                                                                  \
    acc[0][nf_] = __builtin_amdgcn_mfma_f32_16x16x32_bf16(af0, bv_, acc[0][nf_], 0, 0, 0); \
    acc[1][nf_] = __builtin_amdgcn_mfma_f32_16x16x32_bf16(af1, bv_, acc[1][nf_], 0, 0, 0); \
    acc[2][nf_] = __builtin_amdgcn_mfma_f32_16x16x32_bf16(af2, bv_, acc[2][nf_], 0, 0, 0); \
    acc[3][nf_] = __builtin_amdgcn_mfma_f32_16x16x32_bf16(af3, bv_, acc[3][nf_], 0, 0, 0); }

    bf16x8 bq0, bq1, bq2, bq3, bq4;

    // ---- prologue: A(0) -> LDS buf0; preload B frags (0,0..4); issue A(1) ----
    loadA(0);
    writeA(0);                       // compiler inserts vmcnt wait for pv
    bq0 = BFRAG(0, 0); bq1 = BFRAG(0, 1); bq2 = BFRAG(0, 2); bq3 = BFRAG(0, 3); bq4 = BFRAG(0, 4);
    loadA(1);
    asm volatile("s_waitcnt lgkmcnt(0)" ::: "memory");
    __builtin_amdgcn_s_barrier();
    __builtin_amdgcn_sched_barrier(0);

    int cur = 0;
    for (int t = 0; t < KSTEPS; ++t) {
        const unsigned short* Ab = &Alds[cur][0];
        bf16x8 af0 = ARD(0), af1 = ARD(1), af2 = ARD(2), af3 = ARD(3);

        // 10 slots; each consumes frag(t,s) and reloads 5 ahead (rolls into t+1)
        MFMA4(bq0, 0); bq0 = BFRAG(t, 5);
        MFMA4(bq1, 1); bq1 = BFRAG(t, 6);
        MFMA4(bq2, 2); bq2 = BFRAG(t, 7);
        MFMA4(bq3, 3); bq3 = BFRAG(t, 8);
        MFMA4(bq4, 4); bq4 = BFRAG(t, 9);
        MFMA4(bq0, 5); bq0 = BFRAG(t + 1, 0);     // t=79 reads pad step 80 (never consumed)
        MFMA4(bq1, 6); bq1 = BFRAG(t + 1, 1);
        MFMA4(bq2, 7); bq2 = BFRAG(t + 1, 2);
        MFMA4(bq3, 8); bq3 = BFRAG(t + 1, 3);
        MFMA4(bq4, 9); bq4 = BFRAG(t + 1, 4);

        if (t < KSTEPS - 1) {
            writeA(cur ^ 1);                       // A(t+1) regs -> LDS
            int ks2 = t + 2 < KSTEPS ? t + 2 : KSTEPS - 1;
            loadA(ks2);                            // issue A(t+2)
            asm volatile("s_waitcnt lgkmcnt(0)" ::: "memory");
            __builtin_amdgcn_s_barrier();
            __builtin_amdgcn_sched_barrier(0);
        }
        cur ^= 1;
    }

    // ---- epilogue: C/D layout col=lane&15, row=(lane>>4)*4+reg ----
    const int c16 = lane & 15, rg = lane >> 4;
#pragma unroll
    for (int nf = 0; nf < 10; ++nf) {
        int C = wn * 160 + nf * 16 + c16;
        if (C >= NCOLS) continue;
        float bias = (C < O2_) ? b_off[C] : (C < 2 * O2_) ? b_ovoff[C - O2_] : b_on[C - 2 * O2_];
#pragma unroll
        for (int mf = 0; mf < 4; ++mf) {
            int R = mt * BM + wm * 64 + mf * 16 + rg * 4;
            float* o = HSoff + (size_t)R * CSTRIDE + C;
            o[0]           = acc[mf][nf][0] + bias;
            o[CSTRIDE]     = acc[mf][nf][1] + bias;
            o[2 * CSTRIDE] = acc[mf][nf][2] + bias;
            o[3 * CSTRIDE] = acc[mf][nf][3] + bias;
        }
    }
#undef BFRAG
#undef ARD
#undef MFMA4
}

// ---------------- kernel 3: Hon = rowmean over 63 pair rows of cols [392,588) ----------------
__global__ void hon_reduce(const float* __restrict__ HSoff, float* __restrict__ Hon) {
    const int g = blockIdx.x;       // 0..511
    const int t = threadIdx.x;      // 256, t<196 active
    if (t >= O2_) return;
    const float* p0 = HSoff + (size_t)g * NPAIR * CSTRIDE + 2 * O2_ + t;
    const float* p1 = p0 + (size_t)21 * CSTRIDE;
    const float* p2 = p0 + (size_t)42 * CSTRIDE;
    float a0 = 0.f, a1 = 0.f, a2 = 0.f;
#pragma unroll 3
    for (int j = 0; j < 21; ++j) {
        a0 += p0[0]; a1 += p1[0]; a2 += p2[0];
        p0 += CSTRIDE; p1 += CSTRIDE; p2 += CSTRIDE;
    }
    Hon[(size_t)g * O2_ + t] = (a0 + a1 + a2) * (1.f / (float)NPAIR);
}

// ---------------- kernel 4: assemble H and S, LDS-staged, fully coalesced ----------------
__global__ __launch_bounds__(256)
void assemble_k(const float* __restrict__ HSoff, const float* __restrict__ Hon,
                const int* __restrict__ Z, const float* __restrict__ ov_emb,
                const float* __restrict__ orbE, const float* __restrict__ s0E,
                float* __restrict__ H, float* __restrict__ S) {
    __shared__ float Ai[NPAIR * 197];
    __shared__ float Bj[2][16 * 200];
    __shared__ float Dg[O2_];
    __shared__ float Dd[NORB_];

    const int bid = blockIdx.x;
    const int h = bid & 1, i = (bid >> 1) & 63, b = bid >> 7;
    const int t = threadIdx.x;
    const int g = b * A_ + i;
    const int z = Z[g];
    float* out = (h ? S : H) + (size_t)b * AO_ * AO_;

    const float* abase = HSoff + (size_t)g * NPAIR * CSTRIDE + h * O2_;
    for (int u = t; u < NPAIR * O2_; u += 256) {
        int jj = u / O2_, e = u - jj * O2_;
        Ai[jj * 197 + e] = abase[(size_t)jj * CSTRIDE + e];
    }
    if (t < O2_)   Dg[t] = h ? ov_emb[(size_t)z * O2_ + t]   : Hon[(size_t)g * O2_ + t];
    if (t < NORB_) Dd[t] = h ? s0E[(size_t)z * NORB_ + t]    : orbE[(size_t)z * NORB_ + t];

    auto stageB = [&](int buf, int jc) {
        for (int u = t; u < 16 * O2_; u += 256) {
            int jl = u / O2_, e = u - jl * O2_;
            int j = jc * 16 + jl;
            if (j != i) {
                int idx = (i < j) ? i : i - 1;
                Bj[buf][jl * 200 + e] =
                    HSoff[((size_t)(b * A_ + j) * NPAIR + idx) * CSTRIDE + h * O2_ + e];
            }
        }
    };
    stageB(0, 0);
    __syncthreads();

    const int tj = t / NORB_, tq = t - tj * NORB_;   // valid for t<224
    for (int jc = 0; jc < 4; ++jc) {
        if (jc < 3) stageB((jc + 1) & 1, jc + 1);
        if (t < 224) {
            const int j = jc * 16 + tj;
            const int cur = jc & 1;
#pragma unroll
            for (int p = 0; p < NORB_; ++p) {
                float v;
                if (j == i) {
                    v = 0.5f * (Dg[p * NORB_ + tq] + Dg[tq * NORB_ + p]);
                    if (p == tq) v += Dd[p];
                } else {
                    int jj = (j < i) ? j : j - 1;
                    v = 0.5f * (Ai[jj * 197 + p * NORB_ + tq] + Bj[cur][tj * 200 + tq * NORB_ + p]);
                }
                out[(size_t)(i * NORB_ + p) * AO_ + jc * 224 + t] = v;
            }
        }
        __syncthreads();
    }
}

// ---------------- kernel 5: energy head ----------------
__global__ void energy_k(const float* __restrict__ x, const float* __restrict__ W1,
                         const float* __restrict__ b1, const float* __restrict__ W2,
                         const float* __restrict__ b2, float* __restrict__ E) {
    __shared__ float partial[8];
    const int b = blockIdx.x;
    const int lane = threadIdx.x & 63;
    const int w = threadIdx.x >> 6;
    float esum = 0.f;
    for (int aa = 0; aa < 8; ++aa) {
        const int a = w * 8 + aa;
        const float* xr = x + (size_t)(b * A_ + a) * NC_;
        float hj = b1[lane];
        for (int k = 0; k < NC_; ++k) hj = fmaf(xr[k], W1[k * 64 + lane], hj);
        float sp = fmaxf(hj, 0.f) + log1pf(expf(-fabsf(hj))) - 0.69314718055994531f;
        float v = sp * W2[lane];
        for (int off = 32; off; off >>= 1) v += __shfl_down(v, off);
        if (lane == 0) esum += v + b2[0];
    }
    if (lane == 0) partial[w] = esum;
    __syncthreads();
    if (threadIdx.x == 0) {
        float e = 0.f;
        for (int k = 0; k < 8; ++k) e += partial[k];
        E[b] = e;
    }
}

// ---------------- launcher ----------------
extern "C" void kernel_launch(void* const* d_in, const int* in_sizes, int n_in,
                              void* d_out, int out_size, void* d_ws, size_t ws_size,
                              hipStream_t stream) {
    const int*   Z       = (const int*)  d_in[0];
    const float* x       = (const float*)d_in[2];
    const float* V       = (const float*)d_in[3];
    const float* W_off   = (const float*)d_in[4];
    const float* b_off   = (const float*)d_in[5];
    const float* W_on    = (const float*)d_in[6];
    const float* b_on    = (const float*)d_in[7];
    const float* W_ovoff = (const float*)d_in[8];
    const float* b_ovoff = (const float*)d_in[9];
    const float* ov_emb  = (const float*)d_in[10];
    const float* orbE    = (const float*)d_in[11];
    const float* s0E     = (const float*)d_in[12];
    const float* W1      = (const float*)d_in[13];
    const float* b1      = (const float*)d_in[14];
    const float* W2      = (const float*)d_in[15];
    const float* b2      = (const float*)d_in[16];

    float* H = (float*)d_out;
    float* S = H + (size_t)B_ * AO_ * AO_;
    float* E = S + (size_t)B_ * AO_ * AO_;

    char* ws = (char*)d_ws;
    unsigned short* Bws = (unsigned short*)ws;                     // 81 steps x 40960 B = 3,317,760 B (step 80 = pad)
    float* HSoff = (float*)(ws + (size_t)4  * 1024 * 1024);        // 82,575,360 B
    float* Hon   = (float*)(ws + (size_t)88 * 1024 * 1024);        //    401,408 B

    prep_w    <<<KSTEPS, 256, 0, stream>>>(W_off, W_ovoff, W_on, Bws);
    gemm_off  <<<252,    512, 0, stream>>>(V, Bws, b_off, b_ovoff, b_on, HSoff);
    hon_reduce<<<512,    256, 0, stream>>>(HSoff, Hon);
    assemble_k<<<1024,   256, 0, stream>>>(HSoff, Hon, Z, ov_emb, orbE, s0E, H, S);
    energy_k  <<<8,      512, 0, stream>>>(x, W1, b1, W2, b2, E);
}